// Round 14
// baseline (376.713 us; speedup 1.0000x reference)
//
#include <hip/hip_runtime.h>
#include <cstdint>

typedef _Float16 f16;
typedef f16 f16x4 __attribute__((ext_vector_type(4)));
typedef f16 f16x8 __attribute__((ext_vector_type(8)));
typedef float f32x4 __attribute__((ext_vector_type(4)));

#define MFMA16(a, b, c) __builtin_amdgcn_mfma_f32_16x16x32_f16(a, b, c, 0, 0, 0)

static __device__ __forceinline__ void gload16(const void* g, void* l) {
    __builtin_amdgcn_global_load_lds(
        (const __attribute__((address_space(1))) uint32_t*)g,
        (__attribute__((address_space(3))) uint32_t*)l, 16, 0, 0);
}

static __device__ __forceinline__ float blockReduceSum256(float v) {
    __shared__ float red[4];
#pragma unroll
    for (int off = 32; off > 0; off >>= 1) v += __shfl_xor(v, off);
    if ((threadIdx.x & 63) == 0) red[threadIdx.x >> 6] = v;
    __syncthreads();
    return red[0] + red[1] + red[2] + red[3];
}

// ---- per-row ss: sc[row] = sum of squares ----
template <int D>
__global__ __launch_bounds__(256) void k_rowss(const f16* __restrict__ in,
                                               float* __restrict__ sc) {
    constexpr int PER = D / 256;
    size_t row = blockIdx.x;
    const f16* ir = in + row * D;
    int c0 = threadIdx.x * PER;
    float ss = 0.f;
#pragma unroll
    for (int i = 0; i < PER; i += 8) {
        f16x8 h = *reinterpret_cast<const f16x8*>(ir + c0 + i);
#pragma unroll
        for (int e = 0; e < 8; ++e) { float f = (float)h[e]; ss += f * f; }
    }
    ss = blockReduceSum256(ss);
    if (threadIdx.x == 0) sc[row] = ss;
}

// ---- fused prep: rmsnorm(x) (blocks 0..8191), weight casts (+gamma folds),
//      bias concat, sc zeroing (blocks 8192..) ----
__global__ __launch_bounds__(256) void k_prep(
    const float* __restrict__ x, const float* __restrict__ ng, f16* __restrict__ xn,
    const float* __restrict__ Wq_w, const float* __restrict__ Wkv_w,
    const float* __restrict__ W1_w, const float* __restrict__ g1,
    const float* __restrict__ W2_w, const float* __restrict__ g2,
    const float* __restrict__ Wq_b, const float* __restrict__ Wkv_b,
    f16* __restrict__ wqkv, f16* __restrict__ w1, f16* __restrict__ w2,
    float* __restrict__ cb, float* __restrict__ scz) {
    if (blockIdx.x < 8192) {
        size_t row = blockIdx.x;
        const float4 v = reinterpret_cast<const float4*>(x + row * 1024)[threadIdx.x];
        float ss = v.x * v.x + v.y * v.y + v.z * v.z + v.w * v.w;
        ss = blockReduceSum256(ss);
        float sc = 32.0f / fmaxf(sqrtf(ss), 1e-12f);
        const float4 g = reinterpret_cast<const float4*>(ng)[threadIdx.x];
        f16x4 o;
        o[0] = (f16)(v.x * sc * g.x); o[1] = (f16)(v.y * sc * g.y);
        o[2] = (f16)(v.z * sc * g.z); o[3] = (f16)(v.w * sc * g.w);
        *reinterpret_cast<f16x4*>(xn + row * 1024 + threadIdx.x * 4) = o;
        return;
    }
    int i = (blockIdx.x - 8192) * 256 + threadIdx.x;
    if (i < 1048576) {
        float4 v = reinterpret_cast<const float4*>(Wq_w)[i];
        f16x4 o; o[0] = (f16)v.x; o[1] = (f16)v.y; o[2] = (f16)v.z; o[3] = (f16)v.w;
        *reinterpret_cast<f16x4*>(wqkv + (size_t)i * 4) = o;
    } else if (i < 1310720) {
        int j = i - 1048576;
        float4 v = reinterpret_cast<const float4*>(Wkv_w)[j];
        f16x4 o; o[0] = (f16)v.x; o[1] = (f16)v.y; o[2] = (f16)v.z; o[3] = (f16)v.w;
        *reinterpret_cast<f16x4*>(wqkv + 4194304 + (size_t)j * 4) = o;
    } else if (i < 3407872) {
        int j = i - 1310720;
        float4 v = reinterpret_cast<const float4*>(W1_w)[j];
        int c = (j * 4) & 4095;
        f16x4 o;
        o[0] = (f16)(v.x * g1[c]);     o[1] = (f16)(v.y * g1[c + 1]);
        o[2] = (f16)(v.z * g1[c + 2]); o[3] = (f16)(v.w * g1[c + 3]);
        *reinterpret_cast<f16x4*>(w1 + (size_t)j * 4) = o;
    } else if (i < 3932160) {
        int j = i - 3407872;
        float4 v = reinterpret_cast<const float4*>(W2_w)[j];
        int c = (j * 4) & 2047;
        f16x4 o;
        o[0] = (f16)(v.x * g2[c]);     o[1] = (f16)(v.y * g2[c + 1]);
        o[2] = (f16)(v.z * g2[c + 2]); o[3] = (f16)(v.w * g2[c + 3]);
        *reinterpret_cast<f16x4*>(w2 + (size_t)j * 4) = o;
    } else if (i < 3933440) {
        int j = i - 3932160;
        int e = j * 4;
        float4 o4 = (e < 4096) ? reinterpret_cast<const float4*>(Wq_b)[j]
                               : reinterpret_cast<const float4*>(Wkv_b)[(e - 4096) >> 2];
        reinterpret_cast<float4*>(cb)[j] = o4;
    } else if (i < 3937536) {
        int j = i - 3933440;
        reinterpret_cast<float4*>(scz)[j] = make_float4(0.f, 0.f, 0.f, 0.f);
    }
}

// ==== BK=32, 3-slot ring GEMM: 1 barrier + counted vmcnt per K-step ====
// 2 blocks/CU (acc<=64 regs, LDS<=72KB). XCD-chunked. 0-conflict 16x16 swizzle.
// EPI 0: f16. EPI 1: rms+silu f16. EPI 2: rms+silu f32. EPI 3: f16, cols<4096 *0.125.
template <int BM, int BN, int EPI>
__global__ __launch_bounds__(512, 4) void k_gemm3s(const f16* __restrict__ A,
                                                   const f16* __restrict__ Bt,
                                                   const float* __restrict__ bias,
                                                   const float* __restrict__ ssin,
                                                   float sqrtD,
                                                   void* __restrict__ Cout,
                                                   int M, int N, int K) {
    constexpr int WN = BN / 64, WM = 8 / WN, WR = BM / WM;
    constexpr int MW = WR / 16, MH = MW / 2;
    constexpr int LA = BM / 128, LB = BN / 128, LT = LA + LB;
    constexpr int SA = BM * 32, SLOT = SA + BN * 32;

    __shared__ alignas(16) f16 lds[3 * SLOT];

    const int mb = M / BM;
    const int cpx = mb >> 3;
    const int xcd = blockIdx.x & 7;
    const int j = blockIdx.x >> 3;
    const int bm = xcd * cpx + (j % cpx);
    const int bn = j / cpx;

    const int tid = threadIdx.x, w = tid >> 6, l = tid & 63;
    const int wm = w / WN, wn = w % WN;
    const int lrow = l & 15, lq = l >> 4;
    const int g = (lrow >> 1) & 3;

    const f16* Ab = A + (size_t)bm * BM * K;
    const f16* Bb = Bt + (size_t)bn * BN * K;
    const int NT = K >> 5;

    int aoff[MW], boff[4];
#pragma unroll
    for (int m = 0; m < MW; ++m)
        aoff[m] = (wm * WR + m * 16 + lrow) * 32 + 8 * (lq ^ g);
#pragma unroll
    for (int n = 0; n < 4; ++n)
        boff[n] = SA + (wn * 64 + n * 16 + lrow) * 32 + 8 * (lq ^ g);

    auto stage = [&](int t, f16* slot) {
        const int k0 = t << 5;
#pragma unroll
        for (int q = 0; q < LA; ++q) {
            int r = q * 128 + w * 16 + (l >> 2);
            int c = 8 * ((l & 3) ^ ((r >> 1) & 3));
            gload16(Ab + (size_t)r * K + k0 + c, slot + q * 4096 + w * 512);
        }
#pragma unroll
        for (int q = 0; q < LB; ++q) {
            int r = q * 128 + w * 16 + (l >> 2);
            int c = 8 * ((l & 3) ^ ((r >> 1) & 3));
            gload16(Bb + (size_t)r * K + k0 + c, slot + SA + q * 4096 + w * 512);
        }
    };
    auto rdA = [&](f16x8 (&d)[MH], const f16* slot, int h) {
#pragma unroll
        for (int m = 0; m < MH; ++m)
            d[m] = *reinterpret_cast<const f16x8*>(slot + aoff[h * MH + m]);
    };
    auto rdB = [&](f16x8 (&d)[4], const f16* slot) {
#pragma unroll
        for (int n = 0; n < 4; ++n)
            d[n] = *reinterpret_cast<const f16x8*>(slot + boff[n]);
    };

    f32x4 acc[MW][4] = {};
    f16x8 afA[MH], afB[MH], bfA[4];

    auto mfmaLo = [&]() {
#pragma unroll
        for (int m = 0; m < MH; ++m)
#pragma unroll
            for (int n = 0; n < 4; ++n)
                acc[m][n] = MFMA16(afA[m], bfA[n], acc[m][n]);
    };
    auto mfmaHi = [&]() {
#pragma unroll
        for (int m = 0; m < MH; ++m)
#pragma unroll
            for (int n = 0; n < 4; ++n)
                acc[MH + m][n] = MFMA16(afB[m], bfA[n], acc[MH + m][n]);
    };

    // prologue: stage step0 -> slot0, step1 -> slot1; retire step0; preload frags
    f16* s0p = lds;
    f16* s1p = lds + SLOT;
    f16* s2p = lds + 2 * SLOT;
    stage(0, s0p);
    stage(1, s1p);
    asm volatile("s_waitcnt vmcnt(%0)" :: "i"(LT) : "memory");
    __builtin_amdgcn_s_barrier();
    rdA(afA, s0p, 0);
    rdB(bfA, s0p);

    // Ledger: step t reads slot t (afA/bfA preloaded in t-1's tail, afB here) —
    // all precede this step's barrier. stage(t+2)->slot((t+2)%3): that slot's
    // last reads ended in step t-1, separated by step t-1's barrier. vmcnt(LT)
    // retires stage(t+1); barrier publishes; tail reads slot t+1.
    for (int t = 0; t < NT - 2; ++t) {
        rdA(afB, s0p, 1);
        stage(t + 2, s2p);
        mfmaLo();
        mfmaHi();
        __builtin_amdgcn_sched_group_barrier(0x100, 2 * MH, 0);  // afB reads
        __builtin_amdgcn_sched_group_barrier(0x10, LT, 0);       // stage
        __builtin_amdgcn_sched_group_barrier(0x8, MW * 4, 0);    // MFMA
        asm volatile("s_waitcnt vmcnt(%0)" :: "i"(LT) : "memory");
        __builtin_amdgcn_s_barrier();
        rdA(afA, s1p, 0);
        rdB(bfA, s1p);
        f16* tmp = s0p; s0p = s1p; s1p = s2p; s2p = tmp;
    }
    // t = NT-2: no stage; retire stage(NT-1); tail-read slot NT-1
    {
        rdA(afB, s0p, 1);
        mfmaLo();
        mfmaHi();
        asm volatile("s_waitcnt vmcnt(0)" ::: "memory");
        __builtin_amdgcn_s_barrier();
        rdA(afA, s1p, 0);
        rdB(bfA, s1p);
    }
    // t = NT-1
    {
        rdA(afB, s1p, 1);
        mfmaLo();
        mfmaHi();
    }

    // epilogue
    const size_t row0 = (size_t)bm * BM + wm * WR;
    const int col0 = bn * BN + wn * 64;
    float bsv[4];
    bool qc[4];
#pragma unroll
    for (int n = 0; n < 4; ++n) {
        bsv[n] = bias[col0 + n * 16 + lrow];
        qc[n] = (col0 + n * 16) < 4096;
    }
#pragma unroll
    for (int m = 0; m < MW; ++m) {
#pragma unroll
        for (int r = 0; r < 4; ++r) {
            const size_t row = row0 + m * 16 + lq * 4 + r;
            float scl = 1.0f;
            if (EPI == 1 || EPI == 2) scl = sqrtD * rsqrtf(fmaxf(ssin[row], 1e-24f));
#pragma unroll
            for (int n = 0; n < 4; ++n) {
                float v = acc[m][n][r];
                if (EPI == 1 || EPI == 2) v = v * scl;
                v += bsv[n];
                if (EPI == 3 && qc[n]) v *= 0.125f;
                if (EPI == 1 || EPI == 2) v = v / (1.f + __expf(-v));
                const size_t idx = row * (size_t)N + col0 + n * 16 + lrow;
                if (EPI == 2) reinterpret_cast<float*>(Cout)[idx] = v;
                else          reinterpret_cast<f16*>(Cout)[idx] = (f16)v;
            }
        }
    }
}

// ---- windowed GQA attention from combined QKV buffer (row stride 5120) ----
// Q pre-scaled by 1/8 in the QKV epilogue (EPI=3). Accumulates row-ss into ssout.
__global__ __launch_bounds__(256) void k_attn(const f16* __restrict__ qkv,
                                              f16* __restrict__ o,
                                              float* __restrict__ ssout) {
    __shared__ alignas(16) f16 Ksm[64 * 64];
    __shared__ alignas(16) f16 Vtsm[64 * 64];
    __shared__ alignas(16) f16 Psm[4][64 * 64];
    const int idx = blockIdx.x;
    const int s = idx & 127;
    const int g = (idx >> 7) & 7;
    const int b = idx >> 10;
    const int tid = threadIdx.x;
    const int w = tid >> 6, l = tid & 63;

    const int baseR = s * 32 - 16;
#pragma unroll
    for (int i = 0; i < 2; ++i) {
        const int j = i * 32 + (tid >> 3);
        const int d0 = (tid & 7) * 8;
        const int R = baseR + j;
        f16x8 kvv = {}, vvv = {};
        if (R >= 0 && R < 4096) {
            const f16* rp = qkv + ((size_t)(b * 4096 + R)) * 5120 + 4096 + g * 64 + d0;
            kvv = *reinterpret_cast<const f16x8*>(rp);
            vvv = *reinterpret_cast<const f16x8*>(rp + 512);
        }
        *reinterpret_cast<f16x8*>(&Ksm[j * 64 + d0]) = kvv;
#pragma unroll
        for (int e = 0; e < 8; ++e) Vtsm[(d0 + e) * 64 + j] = vvv[e];
    }

    const int lrow = l & 15, lk = (l >> 4) * 8;
    f16x8 aq[4][2];
#pragma unroll
    for (int m = 0; m < 4; ++m) {
        const int qr = w * 64 + m * 16 + lrow;
        const int h = qr >> 5, qi = qr & 31;
        const f16* qp = qkv + ((size_t)(b * 4096 + s * 32 + qi)) * 5120 + (g * 8 + h) * 64 + lk;
        aq[m][0] = *reinterpret_cast<const f16x8*>(qp);
        aq[m][1] = *reinterpret_cast<const f16x8*>(qp + 32);
    }
    __syncthreads();

    f32x4 acc[4][4] = {};
#pragma unroll
    for (int kk = 0; kk < 2; ++kk) {
        f16x8 bk[4];
#pragma unroll
        for (int n = 0; n < 4; ++n)
            bk[n] = *reinterpret_cast<const f16x8*>(&Ksm[(n * 16 + lrow) * 64 + kk * 32 + lk]);
#pragma unroll
        for (int m = 0; m < 4; ++m)
#pragma unroll
            for (int n = 0; n < 4; ++n)
                acc[m][n] = MFMA16(aq[m][kk], bk[n], acc[m][n]);
    }

    const int nlo = (s == 0) ? 1 : 0;
    const int nhi = (s == 127) ? 3 : 4;
#pragma unroll
    for (int m = 0; m < 4; ++m) {
#pragma unroll
        for (int r = 0; r < 4; ++r) {
            float xv[4];
#pragma unroll
            for (int n = 0; n < 4; ++n) xv[n] = acc[m][n][r];
            float mx = -1e30f;
            for (int n = nlo; n < nhi; ++n) mx = fmaxf(mx, xv[n]);
#pragma unroll
            for (int off = 8; off > 0; off >>= 1) mx = fmaxf(mx, __shfl_xor(mx, off));
            float pv[4]; float sum = 0.f;
#pragma unroll
            for (int n = 0; n < 4; ++n) {
                float e = (n >= nlo && n < nhi) ? __expf(xv[n] - mx) : 0.f;
                pv[n] = e; sum += e;
            }
#pragma unroll
            for (int off = 8; off > 0; off >>= 1) sum += __shfl_xor(sum, off);
            const float inv = 1.f / sum;
            const int prow = m * 16 + (l >> 4) * 4 + r;
#pragma unroll
            for (int n = 0; n < 4; ++n)
                Psm[w][prow * 64 + n * 16 + lrow] = (f16)(pv[n] * inv);
        }
    }
    __syncthreads();

    f32x4 oacc[4][4] = {};
#pragma unroll
    for (int kk = 0; kk < 2; ++kk) {
        f16x8 ap[4], bv[4];
#pragma unroll
        for (int m = 0; m < 4; ++m)
            ap[m] = *reinterpret_cast<const f16x8*>(&Psm[w][(m * 16 + lrow) * 64 + kk * 32 + lk]);
#pragma unroll
        for (int n = 0; n < 4; ++n)
            bv[n] = *reinterpret_cast<const f16x8*>(&Vtsm[(n * 16 + lrow) * 64 + kk * 32 + lk]);
#pragma unroll
        for (int m = 0; m < 4; ++m)
#pragma unroll
            for (int n = 0; n < 4; ++n)
                oacc[m][n] = MFMA16(ap[m], bv[n], oacc[m][n]);
    }
    const int lr4 = (l >> 4) * 4;
#pragma unroll
    for (int m = 0; m < 4; ++m) {
#pragma unroll
        for (int r = 0; r < 4; ++r) {
            const int qr = w * 64 + m * 16 + lr4 + r;
            const int h = qr >> 5, qi = qr & 31;
            f16* op = o + ((size_t)(b * 4096 + s * 32 + qi)) * 4096 + (g * 8 + h) * 64;
            float ssp = 0.f;
#pragma unroll
            for (int n = 0; n < 4; ++n) {
                float v = oacc[m][n][r];
                op[n * 16 + lrow] = (f16)v;
                ssp += v * v;
            }
            ssp += __shfl_xor(ssp, 1);
            ssp += __shfl_xor(ssp, 2);
            ssp += __shfl_xor(ssp, 4);
            ssp += __shfl_xor(ssp, 8);
            if (lrow == 0)
                atomicAdd(&ssout[(size_t)(b * 4096 + s * 32 + qi)], ssp);
        }
    }
}

extern "C" void kernel_launch(void* const* d_in, const int* in_sizes, int n_in,
                              void* d_out, int out_size, void* d_ws, size_t ws_size,
                              hipStream_t stream) {
    const float* x     = (const float*)d_in[0];
    const float* ng    = (const float*)d_in[1];
    const float* Wq_w  = (const float*)d_in[2];
    const float* Wq_b  = (const float*)d_in[3];
    const float* Wkv_w = (const float*)d_in[4];
    const float* Wkv_b = (const float*)d_in[5];
    const float* g1    = (const float*)d_in[6];
    const float* W1_w  = (const float*)d_in[7];
    const float* W1_b  = (const float*)d_in[8];
    const float* g2    = (const float*)d_in[9];
    const float* W2_w  = (const float*)d_in[10];
    const float* W2_b  = (const float*)d_in[11];
    float* out = (float*)d_out;

    char* p = (char*)d_ws;
    f16* qkv  = (f16*)(p);                 // [8192][5120] 80 MB
    f16* h1   = (f16*)(p);                 // [8192][2048] (over qkv, after attn)
    f16* xn   = (f16*)(p + 83886080);      // [8192][1024]
    f16* ob   = (f16*)(p + 83886080);      // [8192][4096] (over xn, written by attn)
    f16* w1   = (f16*)(p + 150994944);     // 16 MB
    f16* w2   = (f16*)(p + 167772160);     // 4 MB
    f16* wqkv = (f16*)(p + 171966464);     // [5120][1024] 10 MB
    float* cb  = (float*)(p + 182452224);  // [5120]
    float* sc1 = (float*)(p + 182472704);  // [8192]
    float* sc2 = (float*)(p + 182505472);  // [8192]

    // fused prep: rmsnorm(x) + weight casts (+gamma folds) + bias concat + sc1 zero
    k_prep<<<8192 + 15381, 256, 0, stream>>>(x, ng, xn,
                                             Wq_w, Wkv_w, W1_w, g1, W2_w, g2,
                                             Wq_b, Wkv_b, wqkv, w1, w2, cb, sc1);

    // QKV: [8192,1024] @ [5120,1024]^T -> [8192,5120]; Q cols pre-scaled by 1/8
    k_gemm3s<256, 128, 3><<<1280, 512, 0, stream>>>(xn, wqkv, cb, nullptr, 0.f,
                                                    qkv, 8192, 5120, 1024);

    // attention (writes ob, accumulates sc1 = per-row ss of ob)
    k_attn<<<2048, 256, 0, stream>>>(qkv, ob, sc1);

    // FF1: silu(scl(sc1)*(ob @ (g1.W1)^T) + b1) -> h1  (grid 512 = 2/CU)
    k_gemm3s<256, 128, 1><<<512, 512, 0, stream>>>(ob, w1, W1_b, sc1, 64.0f,
                                                   h1, 8192, 2048, 4096);
    k_rowss<2048><<<8192, 256, 0, stream>>>(h1, sc2);
    // FF2: silu(scl(sc2)*(h1 @ (g2.W2)^T) + b2) -> out f32  (grid 512 = 2/CU)
    k_gemm3s<128, 128, 2><<<512, 512, 0, stream>>>(h1, w2, W2_b, sc2, 45.254834f,
                                                   (void*)out, 8192, 1024, 2048);

    (void)in_sizes; (void)n_in; (void)out_size; (void)ws_size;
}

// Round 15
// 339.793 us; speedup vs baseline: 1.1087x; 1.1087x over previous
//
#include <hip/hip_runtime.h>
#include <cstdint>

typedef _Float16 f16;
typedef f16 f16x4 __attribute__((ext_vector_type(4)));
typedef f16 f16x8 __attribute__((ext_vector_type(8)));
typedef float f32x4 __attribute__((ext_vector_type(4)));

#define MFMA16(a, b, c) __builtin_amdgcn_mfma_f32_16x16x32_f16(a, b, c, 0, 0, 0)

static __device__ __forceinline__ void gload16(const void* g, void* l) {
    __builtin_amdgcn_global_load_lds(
        (const __attribute__((address_space(1))) uint32_t*)g,
        (__attribute__((address_space(3))) uint32_t*)l, 16, 0, 0);
}

// SGB-directed phase layout: NV VMEM (stage), then ND groups of {NM/ND MFMA, 1 DS_READ}
template <int NM, int ND, int NV>
static __device__ __forceinline__ void sgb_phase() {
    if (NV > 0) __builtin_amdgcn_sched_group_barrier(0x10, NV, 0);
    constexpr int PER = NM / ND;
#pragma unroll
    for (int i = 0; i < ND; ++i) {
        if (PER > 0) __builtin_amdgcn_sched_group_barrier(0x8, PER, 0);
        __builtin_amdgcn_sched_group_barrier(0x100, 1, 0);
    }
    if (NM - PER * ND > 0)
        __builtin_amdgcn_sched_group_barrier(0x8, NM - PER * ND, 0);
}

static __device__ __forceinline__ float blockReduceSum256(float v) {
    __shared__ float red[4];
#pragma unroll
    for (int off = 32; off > 0; off >>= 1) v += __shfl_xor(v, off);
    if ((threadIdx.x & 63) == 0) red[threadIdx.x >> 6] = v;
    __syncthreads();
    return red[0] + red[1] + red[2] + red[3];
}

// ---- per-row ss: sc[row] = sum of squares ----
template <int D>
__global__ __launch_bounds__(256) void k_rowss(const f16* __restrict__ in,
                                               float* __restrict__ sc) {
    constexpr int PER = D / 256;
    size_t row = blockIdx.x;
    const f16* ir = in + row * D;
    int c0 = threadIdx.x * PER;
    float ss = 0.f;
#pragma unroll
    for (int i = 0; i < PER; i += 8) {
        f16x8 h = *reinterpret_cast<const f16x8*>(ir + c0 + i);
#pragma unroll
        for (int e = 0; e < 8; ++e) { float f = (float)h[e]; ss += f * f; }
    }
    ss = blockReduceSum256(ss);
    if (threadIdx.x == 0) sc[row] = ss;
}

// ---- fused prep: rmsnorm(x) (blocks 0..8191), weight casts (+gamma folds),
//      bias concat, sc zeroing (blocks 8192..) ----
__global__ __launch_bounds__(256) void k_prep(
    const float* __restrict__ x, const float* __restrict__ ng, f16* __restrict__ xn,
    const float* __restrict__ Wq_w, const float* __restrict__ Wkv_w,
    const float* __restrict__ W1_w, const float* __restrict__ g1,
    const float* __restrict__ W2_w, const float* __restrict__ g2,
    const float* __restrict__ Wq_b, const float* __restrict__ Wkv_b,
    f16* __restrict__ wqkv, f16* __restrict__ w1, f16* __restrict__ w2,
    float* __restrict__ cb, float* __restrict__ scz) {
    if (blockIdx.x < 8192) {
        size_t row = blockIdx.x;
        const float4 v = reinterpret_cast<const float4*>(x + row * 1024)[threadIdx.x];
        float ss = v.x * v.x + v.y * v.y + v.z * v.z + v.w * v.w;
        ss = blockReduceSum256(ss);
        float sc = 32.0f / fmaxf(sqrtf(ss), 1e-12f);
        const float4 g = reinterpret_cast<const float4*>(ng)[threadIdx.x];
        f16x4 o;
        o[0] = (f16)(v.x * sc * g.x); o[1] = (f16)(v.y * sc * g.y);
        o[2] = (f16)(v.z * sc * g.z); o[3] = (f16)(v.w * sc * g.w);
        *reinterpret_cast<f16x4*>(xn + row * 1024 + threadIdx.x * 4) = o;
        return;
    }
    int i = (blockIdx.x - 8192) * 256 + threadIdx.x;
    if (i < 1048576) {
        float4 v = reinterpret_cast<const float4*>(Wq_w)[i];
        f16x4 o; o[0] = (f16)v.x; o[1] = (f16)v.y; o[2] = (f16)v.z; o[3] = (f16)v.w;
        *reinterpret_cast<f16x4*>(wqkv + (size_t)i * 4) = o;
    } else if (i < 1310720) {
        int j = i - 1048576;
        float4 v = reinterpret_cast<const float4*>(Wkv_w)[j];
        f16x4 o; o[0] = (f16)v.x; o[1] = (f16)v.y; o[2] = (f16)v.z; o[3] = (f16)v.w;
        *reinterpret_cast<f16x4*>(wqkv + 4194304 + (size_t)j * 4) = o;
    } else if (i < 3407872) {
        int j = i - 1310720;
        float4 v = reinterpret_cast<const float4*>(W1_w)[j];
        int c = (j * 4) & 4095;
        f16x4 o;
        o[0] = (f16)(v.x * g1[c]);     o[1] = (f16)(v.y * g1[c + 1]);
        o[2] = (f16)(v.z * g1[c + 2]); o[3] = (f16)(v.w * g1[c + 3]);
        *reinterpret_cast<f16x4*>(w1 + (size_t)j * 4) = o;
    } else if (i < 3932160) {
        int j = i - 3407872;
        float4 v = reinterpret_cast<const float4*>(W2_w)[j];
        int c = (j * 4) & 2047;
        f16x4 o;
        o[0] = (f16)(v.x * g2[c]);     o[1] = (f16)(v.y * g2[c + 1]);
        o[2] = (f16)(v.z * g2[c + 2]); o[3] = (f16)(v.w * g2[c + 3]);
        *reinterpret_cast<f16x4*>(w2 + (size_t)j * 4) = o;
    } else if (i < 3933440) {
        int j = i - 3932160;
        int e = j * 4;
        float4 o4 = (e < 4096) ? reinterpret_cast<const float4*>(Wq_b)[j]
                               : reinterpret_cast<const float4*>(Wkv_b)[(e - 4096) >> 2];
        reinterpret_cast<float4*>(cb)[j] = o4;
    } else if (i < 3937536) {
        int j = i - 3933440;
        reinterpret_cast<float4*>(scz)[j] = make_float4(0.f, 0.f, 0.f, 0.f);
    }
}

// ==== 4-phase SGB-interleaved GEMM (16x16x32), XCD-chunked, 2 barriers/K-tile ====
// C[M,N] = A[M,K]@Bt[N,K]^T + bias, with epilogue variants:
// EPI 0: f16 out. EPI 1: rms(ssin)-scale + silu, f16 out.
// EPI 2: rms(ssin)-scale + silu, f32 out. EPI 3: f16 out, cols<4096 scaled 0.125.
template <int BM, int BN, int EPI>
__global__ __launch_bounds__(512, 2) void k_gemm8p(const f16* __restrict__ A,
                                                   const f16* __restrict__ Bt,
                                                   const float* __restrict__ bias,
                                                   const float* __restrict__ ssin,
                                                   float sqrtD,
                                                   void* __restrict__ Cout,
                                                   int M, int N, int K) {
    constexpr int WN = BN / 64, WM = 8 / WN, WR = BM / WM;
    constexpr int MW = WR / 16, MH = MW / 2;
    constexpr int LA = BM / 128, LB = BN / 128;
    constexpr int VS = 2 * LA + LB;
    constexpr int AK = BM * 32;
    constexpr int BKE = BN * 32;
    constexpr int SE = 2 * AK + 2 * BKE;

    __shared__ alignas(16) f16 lds[2 * SE];

    // XCD-chunked: all bn-blocks of one bm-stripe live in one XCD
    const int mb = M / BM;
    const int cpx = mb >> 3;
    const int xcd = blockIdx.x & 7;
    const int j = blockIdx.x >> 3;
    const int bm = xcd * cpx + (j % cpx);
    const int bn = j / cpx;

    const int tid = threadIdx.x, w = tid >> 6, l = tid & 63;
    const int wm = w / WN, wn = w % WN;
    const int lrow = l & 15, lq = l >> 4;
    const int g = (lrow >> 1) & 3;

    const f16* Ab = A + (size_t)bm * BM * K;
    const f16* Bb = Bt + (size_t)bn * BN * K;
    const int NT = K >> 6;

    int aoff[MW], boff[4];
#pragma unroll
    for (int m = 0; m < MW; ++m)
        aoff[m] = (wm * WR + m * 16 + lrow) * 32 + 8 * (lq ^ g);
#pragma unroll
    for (int n = 0; n < 4; ++n)
        boff[n] = (wn * 64 + n * 16 + lrow) * 32 + 8 * (lq ^ g);

    auto stageA = [&](int k0, f16* region) {
#pragma unroll
        for (int q = 0; q < LA; ++q) {
            int r = q * 128 + w * 16 + (l >> 2);
            int c = 8 * ((l & 3) ^ ((r >> 1) & 3));
            gload16(Ab + (size_t)r * K + k0 + c, region + q * 4096 + w * 512);
        }
    };
    auto stageB = [&](int k0, f16* region) {
#pragma unroll
        for (int q = 0; q < LB; ++q) {
            int r = q * 128 + w * 16 + (l >> 2);
            int c = 8 * ((l & 3) ^ ((r >> 1) & 3));
            gload16(Bb + (size_t)r * K + k0 + c, region + q * 4096 + w * 512);
        }
    };
    auto rdA = [&](f16x8 (&d)[MH], const f16* base, int h) {
#pragma unroll
        for (int m = 0; m < MH; ++m)
            d[m] = *reinterpret_cast<const f16x8*>(base + aoff[h * MH + m]);
    };
    auto rdB = [&](f16x8 (&d)[4], const f16* base) {
#pragma unroll
        for (int n = 0; n < 4; ++n)
            d[n] = *reinterpret_cast<const f16x8*>(base + boff[n]);
    };

    f32x4 acc[MW][4] = {};
    f16x8 afA[MH], afB[MH], bfA[4], bfB[4];

    auto mfmaLo = [&](f16x8 (&af)[MH], f16x8 (&bf)[4]) {
#pragma unroll
        for (int m = 0; m < MH; ++m)
#pragma unroll
            for (int n = 0; n < 4; ++n)
                acc[m][n] = MFMA16(af[m], bf[n], acc[m][n]);
    };
    auto mfmaHi = [&](f16x8 (&af)[MH], f16x8 (&bf)[4]) {
#pragma unroll
        for (int m = 0; m < MH; ++m)
#pragma unroll
            for (int n = 0; n < 4; ++n)
                acc[MH + m][n] = MFMA16(af[m], bf[n], acc[MH + m][n]);
    };

    // prologue
    stageA(0, lds);             stageB(0, lds + 2 * AK);
    stageA(32, lds + AK);       stageB(32, lds + 2 * AK + BKE);
    stageA(64, lds + SE);       stageB(64, lds + SE + 2 * AK);
    asm volatile("s_waitcnt vmcnt(%0)" :: "i"(2 * (LA + LB)) : "memory");
    __builtin_amdgcn_s_barrier();
    rdA(afA, lds, 0);
    rdB(bfA, lds + 2 * AK);

    const int NTm2 = NT - 2;
    for (int t = 0; t < NTm2; ++t) {
        f16* s0 = lds + (t & 1) * SE;
        f16* s1 = lds + ((t & 1) ^ 1) * SE;
        const int kn1 = (t + 1) << 6;
        const int kn2 = (t + 2) << 6;
        // ph0: MFMA(M0,kk0) | read af1_kk0 | stage A1(t+1)   [no entry barrier]
        stageA(kn1 + 32, s1 + AK);
        rdA(afB, s0, 1);
        mfmaLo(afA, bfA);
        sgb_phase<MH * 4, MH, LA>();
        // ph1: MFMA(M1,kk0) | read af0_kk1 + bf_kk1 | stage B1(t+1)
        asm volatile("s_waitcnt vmcnt(%0)" :: "i"(VS) : "memory");
        __builtin_amdgcn_s_barrier();
        stageB(kn1 + 32, s1 + 2 * AK + BKE);
        rdA(afA, s0 + AK, 0);
        rdB(bfB, s0 + 2 * AK + BKE);
        mfmaHi(afB, bfA);
        sgb_phase<MH * 4, MH + 4, LB>();
        // ph2: MFMA(M0,kk1) | read af1_kk1 | stage A0(t+2)   [no entry barrier]
        stageA(kn2, s0);
        rdA(afB, s0 + AK, 1);
        mfmaLo(afA, bfB);
        sgb_phase<MH * 4, MH, LA>();
        // ph3: MFMA(M1,kk1) | read af0_kk0(t+1) + bf_kk0(t+1) | stage B0(t+2)
        asm volatile("s_waitcnt vmcnt(%0)" :: "i"(VS) : "memory");
        __builtin_amdgcn_s_barrier();
        stageB(kn2, s0 + 2 * AK);
        rdA(afA, s1, 0);
        rdB(bfA, s1 + 2 * AK);
        mfmaHi(afB, bfB);
        sgb_phase<MH * 4, MH + 4, LB>();
    }
    // t = NT-2
    {
        const int t = NTm2;
        f16* s0 = lds + (t & 1) * SE;
        f16* s1 = lds + ((t & 1) ^ 1) * SE;
        const int kn1 = (t + 1) << 6;
        stageA(kn1 + 32, s1 + AK);
        rdA(afB, s0, 1);
        mfmaLo(afA, bfA);
        sgb_phase<MH * 4, MH, LA>();
        asm volatile("s_waitcnt vmcnt(%0)" :: "i"(VS) : "memory");
        __builtin_amdgcn_s_barrier();
        stageB(kn1 + 32, s1 + 2 * AK + BKE);
        rdA(afA, s0 + AK, 0);
        rdB(bfB, s0 + 2 * AK + BKE);
        mfmaHi(afB, bfA);
        sgb_phase<MH * 4, MH + 4, LB>();
        rdA(afB, s0 + AK, 1);
        mfmaLo(afA, bfB);
        sgb_phase<MH * 4, MH, 0>();
        asm volatile("s_waitcnt vmcnt(%0)" :: "i"(LA + LB) : "memory");
        __builtin_amdgcn_s_barrier();
        rdA(afA, s1, 0);
        rdB(bfA, s1 + 2 * AK);
        mfmaHi(afB, bfB);
        sgb_phase<MH * 4, MH + 4, 0>();
    }
    // t = NT-1
    {
        f16* s0 = lds + ((NT - 1) & 1) * SE;
        rdA(afB, s0, 1);
        mfmaLo(afA, bfA);
        sgb_phase<MH * 4, MH, 0>();
        asm volatile("s_waitcnt vmcnt(0)" ::: "memory");
        __builtin_amdgcn_s_barrier();
        rdA(afA, s0 + AK, 0);
        rdB(bfB, s0 + 2 * AK + BKE);
        mfmaHi(afB, bfA);
        sgb_phase<MH * 4, MH + 4, 0>();
        rdA(afB, s0 + AK, 1);
        mfmaLo(afA, bfB);
        sgb_phase<MH * 4, MH, 0>();
        mfmaHi(afB, bfB);
    }

    // epilogue
    const size_t row0 = (size_t)bm * BM + wm * WR;
    const int col0 = bn * BN + wn * 64;
    float bsv[4];
    bool qc[4];
#pragma unroll
    for (int n = 0; n < 4; ++n) {
        bsv[n] = bias[col0 + n * 16 + lrow];
        qc[n] = (col0 + n * 16) < 4096;
    }
#pragma unroll
    for (int m = 0; m < MW; ++m) {
#pragma unroll
        for (int r = 0; r < 4; ++r) {
            const size_t row = row0 + m * 16 + lq * 4 + r;
            float scl = 1.0f;
            if (EPI == 1 || EPI == 2) scl = sqrtD * rsqrtf(fmaxf(ssin[row], 1e-24f));
#pragma unroll
            for (int n = 0; n < 4; ++n) {
                float v = acc[m][n][r];
                if (EPI == 1 || EPI == 2) v = v * scl;
                v += bsv[n];
                if (EPI == 3 && qc[n]) v *= 0.125f;   // fold attn 1/sqrt(DQ)
                if (EPI == 1 || EPI == 2) v = v / (1.f + __expf(-v));
                const size_t idx = row * (size_t)N + col0 + n * 16 + lrow;
                if (EPI == 2) reinterpret_cast<float*>(Cout)[idx] = v;
                else          reinterpret_cast<f16*>(Cout)[idx] = (f16)v;
            }
        }
    }
}

// ---- windowed GQA attention from combined QKV buffer (row stride 5120) ----
// Q already pre-scaled by 1/8 in the QKV epilogue (EPI=3).
// Accumulates per-row sum of squares of output into ssout (pre-zeroed).
__global__ __launch_bounds__(256) void k_attn(const f16* __restrict__ qkv,
                                              f16* __restrict__ o,
                                              float* __restrict__ ssout) {
    __shared__ alignas(16) f16 Ksm[64 * 64];
    __shared__ alignas(16) f16 Vtsm[64 * 64];
    __shared__ alignas(16) f16 Psm[4][64 * 64];
    const int idx = blockIdx.x;
    const int s = idx & 127;
    const int g = (idx >> 7) & 7;
    const int b = idx >> 10;
    const int tid = threadIdx.x;
    const int w = tid >> 6, l = tid & 63;

    const int baseR = s * 32 - 16;
#pragma unroll
    for (int i = 0; i < 2; ++i) {
        const int j = i * 32 + (tid >> 3);
        const int d0 = (tid & 7) * 8;
        const int R = baseR + j;
        f16x8 kvv = {}, vvv = {};
        if (R >= 0 && R < 4096) {
            const f16* rp = qkv + ((size_t)(b * 4096 + R)) * 5120 + 4096 + g * 64 + d0;
            kvv = *reinterpret_cast<const f16x8*>(rp);
            vvv = *reinterpret_cast<const f16x8*>(rp + 512);
        }
        *reinterpret_cast<f16x8*>(&Ksm[j * 64 + d0]) = kvv;
#pragma unroll
        for (int e = 0; e < 8; ++e) Vtsm[(d0 + e) * 64 + j] = vvv[e];
    }

    const int lrow = l & 15, lk = (l >> 4) * 8;
    f16x8 aq[4][2];
#pragma unroll
    for (int m = 0; m < 4; ++m) {
        const int qr = w * 64 + m * 16 + lrow;
        const int h = qr >> 5, qi = qr & 31;
        const f16* qp = qkv + ((size_t)(b * 4096 + s * 32 + qi)) * 5120 + (g * 8 + h) * 64 + lk;
        aq[m][0] = *reinterpret_cast<const f16x8*>(qp);
        aq[m][1] = *reinterpret_cast<const f16x8*>(qp + 32);
    }
    __syncthreads();

    f32x4 acc[4][4] = {};
#pragma unroll
    for (int kk = 0; kk < 2; ++kk) {
        f16x8 bk[4];
#pragma unroll
        for (int n = 0; n < 4; ++n)
            bk[n] = *reinterpret_cast<const f16x8*>(&Ksm[(n * 16 + lrow) * 64 + kk * 32 + lk]);
#pragma unroll
        for (int m = 0; m < 4; ++m)
#pragma unroll
            for (int n = 0; n < 4; ++n)
                acc[m][n] = MFMA16(aq[m][kk], bk[n], acc[m][n]);
    }

    const int nlo = (s == 0) ? 1 : 0;
    const int nhi = (s == 127) ? 3 : 4;
#pragma unroll
    for (int m = 0; m < 4; ++m) {
#pragma unroll
        for (int r = 0; r < 4; ++r) {
            float xv[4];
#pragma unroll
            for (int n = 0; n < 4; ++n) xv[n] = acc[m][n][r];   // Q pre-scaled
            float mx = -1e30f;
            for (int n = nlo; n < nhi; ++n) mx = fmaxf(mx, xv[n]);
#pragma unroll
            for (int off = 8; off > 0; off >>= 1) mx = fmaxf(mx, __shfl_xor(mx, off));
            float pv[4]; float sum = 0.f;
#pragma unroll
            for (int n = 0; n < 4; ++n) {
                float e = (n >= nlo && n < nhi) ? __expf(xv[n] - mx) : 0.f;
                pv[n] = e; sum += e;
            }
#pragma unroll
            for (int off = 8; off > 0; off >>= 1) sum += __shfl_xor(sum, off);
            const float inv = 1.f / sum;
            const int prow = m * 16 + (l >> 4) * 4 + r;
#pragma unroll
            for (int n = 0; n < 4; ++n)
                Psm[w][prow * 64 + n * 16 + lrow] = (f16)(pv[n] * inv);
        }
    }
    __syncthreads();

    f32x4 oacc[4][4] = {};
#pragma unroll
    for (int kk = 0; kk < 2; ++kk) {
        f16x8 ap[4], bv[4];
#pragma unroll
        for (int m = 0; m < 4; ++m)
            ap[m] = *reinterpret_cast<const f16x8*>(&Psm[w][(m * 16 + lrow) * 64 + kk * 32 + lk]);
#pragma unroll
        for (int n = 0; n < 4; ++n)
            bv[n] = *reinterpret_cast<const f16x8*>(&Vtsm[(n * 16 + lrow) * 64 + kk * 32 + lk]);
#pragma unroll
        for (int m = 0; m < 4; ++m)
#pragma unroll
            for (int n = 0; n < 4; ++n)
                oacc[m][n] = MFMA16(ap[m], bv[n], oacc[m][n]);
    }
    const int lr4 = (l >> 4) * 4;
#pragma unroll
    for (int m = 0; m < 4; ++m) {
#pragma unroll
        for (int r = 0; r < 4; ++r) {
            const int qr = w * 64 + m * 16 + lr4 + r;
            const int h = qr >> 5, qi = qr & 31;
            f16* op = o + ((size_t)(b * 4096 + s * 32 + qi)) * 4096 + (g * 8 + h) * 64;
            float ssp = 0.f;
#pragma unroll
            for (int n = 0; n < 4; ++n) {
                float v = oacc[m][n][r];
                op[n * 16 + lrow] = (f16)v;
                ssp += v * v;
            }
            ssp += __shfl_xor(ssp, 1);
            ssp += __shfl_xor(ssp, 2);
            ssp += __shfl_xor(ssp, 4);
            ssp += __shfl_xor(ssp, 8);
            if (lrow == 0)
                atomicAdd(&ssout[(size_t)(b * 4096 + s * 32 + qi)], ssp);
        }
    }
}

extern "C" void kernel_launch(void* const* d_in, const int* in_sizes, int n_in,
                              void* d_out, int out_size, void* d_ws, size_t ws_size,
                              hipStream_t stream) {
    const float* x     = (const float*)d_in[0];
    const float* ng    = (const float*)d_in[1];
    const float* Wq_w  = (const float*)d_in[2];
    const float* Wq_b  = (const float*)d_in[3];
    const float* Wkv_w = (const float*)d_in[4];
    const float* Wkv_b = (const float*)d_in[5];
    const float* g1    = (const float*)d_in[6];
    const float* W1_w  = (const float*)d_in[7];
    const float* W1_b  = (const float*)d_in[8];
    const float* g2    = (const float*)d_in[9];
    const float* W2_w  = (const float*)d_in[10];
    const float* W2_b  = (const float*)d_in[11];
    float* out = (float*)d_out;

    char* p = (char*)d_ws;
    f16* qkv  = (f16*)(p);                 // [8192][5120] 80 MB
    f16* h1   = (f16*)(p);                 // [8192][2048] (over qkv, after attn)
    f16* xn   = (f16*)(p + 83886080);      // [8192][1024]
    f16* ob   = (f16*)(p + 83886080);      // [8192][4096] (over xn, written by attn)
    f16* w1   = (f16*)(p + 150994944);     // 16 MB
    f16* w2   = (f16*)(p + 167772160);     // 4 MB
    f16* wqkv = (f16*)(p + 171966464);     // [5120][1024] 10 MB
    float* cb  = (float*)(p + 182452224);  // [5120]
    float* sc1 = (float*)(p + 182472704);  // [8192]
    float* sc2 = (float*)(p + 182505472);  // [8192]

    // fused prep: rmsnorm(x) + weight casts (+gamma folds) + bias concat + sc1 zero
    k_prep<<<8192 + 15381, 256, 0, stream>>>(x, ng, xn,
                                             Wq_w, Wkv_w, W1_w, g1, W2_w, g2,
                                             Wq_b, Wkv_b, wqkv, w1, w2, cb, sc1);

    // QKV: [8192,1024] @ [5120,1024]^T -> [8192,5120]; Q cols pre-scaled by 1/8
    k_gemm8p<256, 256, 3><<<640, 512, 0, stream>>>(xn, wqkv, cb, nullptr, 0.f,
                                                   qkv, 8192, 5120, 1024);

    // attention (writes ob, accumulates sc1 = per-row ss of ob)
    k_attn<<<2048, 256, 0, stream>>>(qkv, ob, sc1);

    // FF1: silu(scl(sc1)*(ob @ (g1.W1)^T) + b1) -> h1
    k_gemm8p<256, 256, 1><<<256, 512, 0, stream>>>(ob, w1, W1_b, sc1, 64.0f,
                                                   h1, 8192, 2048, 4096);
    k_rowss<2048><<<8192, 256, 0, stream>>>(h1, sc2);
    // FF2: silu(scl(sc2)*(h1 @ (g2.W2)^T) + b2) -> out f32
    k_gemm8p<256, 128, 2><<<256, 512, 0, stream>>>(h1, w2, W2_b, sc2, 45.254834f,
                                                   (void*)out, 8192, 1024, 2048);

    (void)in_sizes; (void)n_in; (void)out_size; (void)ws_size;
}